// Round 3
// baseline (248.713 us; speedup 1.0000x reference)
//
#include <hip/hip_runtime.h>
#include <hip/hip_bf16.h>

#define NSEQ 4096
#define CDIM 256
#define CQKD 32
#define LOG2E 1.4426950408889634f

typedef float v4f __attribute__((ext_vector_type(4)));
typedef float v16f __attribute__((ext_vector_type(16)));
typedef short v8s __attribute__((ext_vector_type(8)));
typedef unsigned long long u64;

__device__ __forceinline__ float exp2_(float x) {
#if __has_builtin(__builtin_amdgcn_exp2f)
  return __builtin_amdgcn_exp2f(x);
#else
  float r;
  __asm__("v_exp_f32 %0, %1" : "=v"(r) : "v"(x));
  return r;
#endif
}

__device__ __forceinline__ unsigned short f2bf(float x) {
  unsigned u = __builtin_bit_cast(unsigned, x);
  unsigned r = (u + 0x7FFFu + ((u >> 16) & 1u)) >> 16;
  return (unsigned short)r;
}
__device__ __forceinline__ float bf2f(unsigned short s) {
  unsigned u = ((unsigned)s) << 16;
  return __builtin_bit_cast(float, u);
}
__device__ __forceinline__ unsigned int pack_bf16(float a, float b) {
#if __has_builtin(__builtin_amdgcn_cvt_pk_bf16_f32)
  typedef __bf16 v2bf __attribute__((ext_vector_type(2)));
  v2bf r = __builtin_amdgcn_cvt_pk_bf16_f32(a, b);
  return __builtin_bit_cast(unsigned int, r);
#else
  return ((unsigned)f2bf(b) << 16) | (unsigned)f2bf(a);
#endif
}

// fp8 e4m3fn (OCP) encode, software fallback
__device__ __forceinline__ unsigned char f2e4m3(float x) {
  unsigned u = __builtin_bit_cast(unsigned, x);
  unsigned s = (u >> 24) & 0x80u;
  unsigned au = u & 0x7fffffffu;
  if (au > 0x43e00000u) return (unsigned char)(s | 0x7eu);  // clamp to 448
  if (au < 0x3c800000u) {                                   // subnormal range (<2^-6)
    float ax = __builtin_bit_cast(float, au);
    int q = (int)(ax * 512.0f + 0.5f);
    if (q > 7) q = 7;
    return (unsigned char)(s | (unsigned)q);
  }
  int e = (int)((au >> 23) & 0xffu) - 127 + 7;
  unsigned m = au & 0x7fffffu;
  unsigned mr = m + 0x7ffffu + ((m >> 20) & 1u);
  if (mr >= 0x800000u) { mr -= 0x800000u; e += 1; if (e >= 16) return (unsigned char)(s | 0x7e); }
  return (unsigned char)(s | ((unsigned)e << 3) | (mr >> 20));
}
__device__ __forceinline__ unsigned int pack4_fp8(float a, float b, float c, float d) {
#if __has_builtin(__builtin_amdgcn_cvt_pk_fp8_f32)
  int v = 0;
  v = __builtin_amdgcn_cvt_pk_fp8_f32(a, b, v, false);
  v = __builtin_amdgcn_cvt_pk_fp8_f32(c, d, v, true);
  return (unsigned int)v;
#else
  return (unsigned)f2e4m3(a) | ((unsigned)f2e4m3(b) << 8) |
         ((unsigned)f2e4m3(c) << 16) | ((unsigned)f2e4m3(d) << 24);
#endif
}

// ---------------- weight convert+frag-pack (bf16) ----------------
__global__ __launch_bounds__(256) void convw_kernel(
    const float* __restrict__ q1w, const float* __restrict__ k1w,
    const float* __restrict__ k2w, const float* __restrict__ q2w,
    const float* __restrict__ v1w, const float* __restrict__ v2w,
    unsigned short* __restrict__ W) {
  const int s = blockIdx.x * 256 + threadIdx.x;  // v8s slot, 20480 total
  const float* src;
  int o, ch0;
  size_t obase;
  float scale = 1.0f;
  if (s < 3072) {
    const int wsel = s >> 10, r = s & 1023;
    src = wsel == 0 ? q1w : (wsel == 1 ? k1w : k2w);
    const int ot = r >> 9, cb = (r >> 6) & 7, lane = r & 63;
    o = ot * 16 + (lane & 15);
    ch0 = cb * 32 + ((lane >> 4) & 3) * 8;
    obase = (size_t)wsel * 8192 + (size_t)r * 8;
  } else if (s < 19456) {
    const int s2 = s - 3072, which = s2 >> 13, r = s2 & 8191;
    src = which == 0 ? v1w : v2w;
    const int ot = r >> 9, cb = (r >> 6) & 7, lane = r & 63;
    o = ot * 16 + (lane & 15);
    ch0 = cb * 32 + ((lane >> 4) & 3) * 8;
    obase = 32768 + (size_t)which * 65536 + (size_t)r * 8;
  } else {
    const int r = s - 19456;
    src = q2w;
    const int lane = r & 63;
    o = lane & 31;
    ch0 = (r >> 6) * 16 + (lane >> 5) * 8;
    obase = 24576 + (size_t)r * 8;
    scale = LOG2E;
  }
#pragma unroll
  for (int j = 0; j < 8; ++j)
    W[obase + j] = f2bf(src[o * CDIM + ch0 + j] * scale);
}

// ---------------- prep: transpose + Q/K/V projections (V emitted fp8) ----------------
__global__ __launch_bounds__(256) void prep_kernel(
    const float* __restrict__ x, const float* __restrict__ y,
    const float* __restrict__ z, const unsigned short* __restrict__ Wbf,
    const float* __restrict__ q1b, const float* __restrict__ k1b,
    const float* __restrict__ k2b, const float* __restrict__ v1b,
    const float* __restrict__ v2b, unsigned short* __restrict__ Q1,
    unsigned short* __restrict__ K1, unsigned short* __restrict__ K2,
    unsigned char* __restrict__ V1, unsigned char* __restrict__ V2) {
  __shared__ unsigned short t[256][72];  // staging [ch][n] bf16; reused as fp8 Vt
  __shared__ unsigned short Kt[64][40];
  const int src = blockIdx.z;
  const float* in = src == 0 ? x : (src == 1 ? y : z);
  const int b = blockIdx.y;
  const int n0 = blockIdx.x * 64;
  const int tid = threadIdx.x, lane = tid & 63, w = tid >> 6;
  const int quad = lane >> 4, r15 = lane & 15, l31 = lane & 31, lh = lane >> 5;
  const float* ip = in + (size_t)(b * CDIM) * NSEQ + n0;
  {
    const int chb = tid >> 4, c4 = (tid & 15) * 4;
#pragma unroll
    for (int p = 0; p < 16; ++p) {
      const int ch = p * 16 + chb;
      float4 v = *(const float4*)(ip + (size_t)ch * NSEQ + c4);
      uint2 pk;
      pk.x = pack_bf16(v.x, v.y);
      pk.y = pack_bf16(v.z, v.w);
      *(uint2*)&t[ch][c4] = pk;
    }
  }
  __syncthreads();
  v8s af[8];
#pragma unroll
  for (int cb = 0; cb < 8; ++cb) {
    union { unsigned short e[8]; v8s v; } u;
#pragma unroll
    for (int j = 0; j < 8; ++j) u.e[j] = t[cb * 32 + quad * 8 + j][w * 16 + r15];
    af[cb] = u.v;
  }
  const int nt = blockIdx.x * 4 + w;
  const unsigned short* Wqk = Wbf + src * 8192;
  v4f a0 = {0.f, 0.f, 0.f, 0.f}, a1 = a0;
#pragma unroll
  for (int cb = 0; cb < 8; ++cb) {
    v8s b0 = *(const v8s*)(Wqk + (size_t)cb * 512 + lane * 8);
    v8s b1 = *(const v8s*)(Wqk + (size_t)(8 + cb) * 512 + lane * 8);
    a0 = __builtin_amdgcn_mfma_f32_16x16x32_bf16(af[cb], b0, a0, 0, 0, 0);
    a1 = __builtin_amdgcn_mfma_f32_16x16x32_bf16(af[cb], b1, a1, 0, 0, 0);
  }
  if (src == 0) {
#pragma unroll
    for (int r = 0; r < 4; ++r) {
      Q1[((size_t)b * NSEQ + nt * 16 + quad * 4 + r) * CQKD + r15] =
          f2bf((a0[r] + q1b[r15]) * LOG2E);
      Q1[((size_t)b * NSEQ + nt * 16 + quad * 4 + r) * CQKD + 16 + r15] =
          f2bf((a1[r] + q1b[16 + r15]) * LOG2E);
    }
    return;
  }
  const float* kbias = src == 1 ? k1b : k2b;
#pragma unroll
  for (int r = 0; r < 4; ++r) {
    Kt[w * 16 + quad * 4 + r][r15] = f2bf(a0[r] + kbias[r15]);
    Kt[w * 16 + quad * 4 + r][16 + r15] = f2bf(a1[r] + kbias[16 + r15]);
  }
  const unsigned short* Wv = Wbf + 32768 + (src - 1) * 65536;
  const float* vbias = src == 1 ? v1b : v2b;
  v4f vacc[16];
#pragma unroll
  for (int ot = 0; ot < 16; ++ot) vacc[ot] = (v4f){0.f, 0.f, 0.f, 0.f};
#pragma unroll
  for (int cb = 0; cb < 8; ++cb) {
    const v8s afc = af[cb];
#pragma unroll
    for (int ot = 0; ot < 16; ++ot) {
      v8s bf = *(const v8s*)(Wv + (size_t)(ot * 8 + cb) * 512 + lane * 8);
      vacc[ot] = __builtin_amdgcn_mfma_f32_16x16x32_bf16(afc, bf, vacc[ot], 0, 0, 0);
    }
  }
  __syncthreads();  // staging reads done -> reuse t as fp8 Vt (rows 72 B)
  unsigned char* Vt8 = (unsigned char*)t;
#pragma unroll
  for (int ot = 0; ot < 16; ++ot) {
    const int ch = ot * 16 + r15;
    const float bv = vbias[ch];
    *(unsigned int*)&Vt8[(size_t)ch * 72 + w * 16 + quad * 4] =
        pack4_fp8(vacc[ot][0] + bv, vacc[ot][1] + bv, vacc[ot][2] + bv, vacc[ot][3] + bv);
  }
  {
    unsigned short* Kout = (src == 1 ? K1 : K2) + (size_t)b * (NSEQ / 16) * 512;
    *(v8s*)(Kout + ((size_t)nt * 64 + lane) * 8) = *(const v8s*)&Kt[w * 16 + r15][quad * 8];
  }
  __syncthreads();  // Vt complete
  unsigned char* Vout = (src == 1 ? V1 : V2) + (size_t)b * (NSEQ / 16) * 8 * 512;
#pragma unroll
  for (int chb = 0; chb < 8; ++chb)
    *(u64*)(Vout + (((size_t)nt * 8 + chb) * 64 + lane) * 8) =
        *(const u64*)&Vt8[(size_t)(chb * 32 + l31) * 72 + w * 16 + lh * 8];
}

// ---------------- fused double attention v3: barrier-free K-loop ----------------
// 512 thr = 8 waves = 2 q-groups x 4 key-splits. Wave owns 32 q (q = lane&31),
// 1024 keys. Swapped QK^T (mfma(K,Q)) puts P lane-local: online softmax fully
// in-register (defer-max THR=8 -> P <= 2^8 < 448, e4m3-safe). PV B-frags built
// via 4x shfl_xor(32). NO barriers / NO LDS in the K-loop; waves free-run.
// Partials (m, lsum, acc) merged across key-splits once per layer via LDS tree.

__device__ __forceinline__ void attn_ks(
    const unsigned short* __restrict__ Kp, const unsigned char* __restrict__ Vp,
    const v8s qfA, const v8s qfB, int ks, int lane,
    v16f acc[8], float& m, float& lsum) {
  const int l31 = lane & 31, lh = lane >> 5;
  // K row-major [key][32ch] frags: byte = (key>>4)*1024 + (chunk*2+lh)*256 + (key&15)*16
  const char* Kb = (const char*)Kp + (size_t)ks * 65536 + (size_t)(l31 >> 4) * 1024 +
                   (size_t)lh * 256 + (size_t)(l31 & 15) * 16;
  // V: byte = ng*4096 + slab*512 + lane*8, ng = ks*64 + 2t + ksl
  const char* Vb = (const char*)Vp + (size_t)ks * 262144 + (size_t)lane * 8;
  m = -3.0e38f;
  lsum = 0.f;
  v8s kA = *(const v8s*)(Kb);
  v8s kB = *(const v8s*)(Kb + 512);
#pragma unroll 1
  for (int t = 0; t < 32; ++t) {
    // V tile loads (keys t*32.. : ksl0 then ksl1), consumed ~250 cyc later
    u64 v0[8], v1[8];
#pragma unroll
    for (int s = 0; s < 8; ++s) v0[s] = *(const u64*)(Vb + (size_t)t * 8192 + s * 512);
#pragma unroll
    for (int s = 0; s < 8; ++s) v1[s] = *(const u64*)(Vb + (size_t)t * 8192 + 4096 + s * 512);
    // S' = K.Q^T : D[key_row][q=l31], key_row = (reg&3)+8*(reg>>2)+4*lh
    v16f st = (v16f)(0.f);
    st = __builtin_amdgcn_mfma_f32_32x32x16_bf16(kA, qfA, st, 0, 0, 0);
    st = __builtin_amdgcn_mfma_f32_32x32x16_bf16(kB, qfB, st, 0, 0, 0);
    if (t < 31) {  // prefetch next K tile
      kA = *(const v8s*)(Kb + (size_t)(t + 1) * 2048);
      kB = *(const v8s*)(Kb + (size_t)(t + 1) * 2048 + 512);
    }
    // online max (defer, THR=8)
    float tmax = st[0];
#pragma unroll
    for (int g = 1; g < 16; ++g) tmax = fmaxf(tmax, st[g]);
    tmax = fmaxf(tmax, __shfl_xor(tmax, 32));
    if (__any(tmax > m + 8.0f)) {
      float mn = fmaxf(m, tmax);
      float sc = exp2_(m - mn);
#pragma unroll
      for (int s = 0; s < 8; ++s) acc[s] *= sc;
      lsum *= sc;
      m = mn;
    }
    // exp2 + fp8 pack (P = exp2(st - m) <= 2^8)
    float esum = 0.f;
    unsigned pw[4];
#pragma unroll
    for (int h = 0; h < 4; ++h) {
      float e0 = exp2_(st[4 * h + 0] - m), e1 = exp2_(st[4 * h + 1] - m);
      float e2 = exp2_(st[4 * h + 2] - m), e3 = exp2_(st[4 * h + 3] - m);
      esum += (e0 + e1) + (e2 + e3);
      pw[h] = pack4_fp8(e0, e1, e2, e3);
    }
    lsum += esum;
    // build PV B-frags: k = lh*8+j lane-mapping; partner half via shfl_xor(32)
    unsigned X0 = (unsigned)__shfl_xor((int)pw[0], 32);
    unsigned X1 = (unsigned)__shfl_xor((int)pw[1], 32);
    unsigned X2 = (unsigned)__shfl_xor((int)pw[2], 32);
    unsigned X3 = (unsigned)__shfl_xor((int)pw[3], 32);
    u64 fA = lh ? ((u64)X1 | ((u64)pw[1] << 32)) : ((u64)pw[0] | ((u64)X0 << 32));
    u64 fB = lh ? ((u64)X3 | ((u64)pw[3] << 32)) : ((u64)pw[2] | ((u64)X2 << 32));
    // PV: acc[slab] += V[slab,k] * P^T
#pragma unroll
    for (int s = 0; s < 8; ++s) {
      acc[s] = __builtin_amdgcn_mfma_f32_32x32x16_fp8_fp8((long)v0[s], (long)fA, acc[s], 0, 0, 0);
      acc[s] = __builtin_amdgcn_mfma_f32_32x32x16_fp8_fp8((long)v1[s], (long)fB, acc[s], 0, 0, 0);
    }
  }
  lsum += __shfl_xor(lsum, 32);  // both 16-key halves -> per-q total
}

__global__ __launch_bounds__(512, 2) void fused_attn_kernel(
    const unsigned short* __restrict__ Q1g, const unsigned short* __restrict__ K1g,
    const unsigned char* __restrict__ V1g, const unsigned short* __restrict__ K2g,
    const unsigned char* __restrict__ V2g, const unsigned short* __restrict__ W2g,
    const float* __restrict__ x, const float* __restrict__ q2b,
    const float* __restrict__ g1p, const float* __restrict__ g2p,
    float* __restrict__ outp) {
  __shared__ float cb[2][256][32];                         // 64 KB combine scratch
  __shared__ __align__(16) unsigned short out1T[64 * 264]; // 33.8 KB [q][c] bf16
  __shared__ __align__(16) unsigned short q2s[64 * 32];    // 4 KB [q][o]
  __shared__ float mbuf[8][32];
  __shared__ float sbuf[8][32];

  const int tid = threadIdx.x;
  const int lane = tid & 63;
  const int w = tid >> 6;
  const int qg = w >> 2;   // q-group (0..1): q rows qg*32..+31
  const int ks = w & 3;    // key-split (0..3): keys ks*1024..+1023
  const int l31 = lane & 31, lh = lane >> 5;
  const int b = blockIdx.x & 3;
  const int n0 = (blockIdx.x >> 2) * 64;
  const int q = qg * 32 + l31;  // block-local q row

  const float g1 = g1p[0];
  const float g2 = g2p[0];

  const unsigned short* Qp  = Q1g + (size_t)b * NSEQ * CQKD;
  const unsigned short* K1p = K1g + (size_t)b * (NSEQ / 16) * 512;
  const unsigned short* K2p = K2g + (size_t)b * (NSEQ / 16) * 512;
  const unsigned char* V1p  = V1g + (size_t)b * (NSEQ / 16) * 8 * 512;
  const unsigned char* V2p  = V2g + (size_t)b * (NSEQ / 16) * 8 * 512;

  v16f acc[8];
#pragma unroll
  for (int s = 0; s < 8; ++s) acc[s] = (v16f)(0.f);
  float m, lsum;

  // ---- layer 1 ----
  {
    v8s qfA = *(const v8s*)(Qp + (size_t)(n0 + q) * CQKD + lh * 8);
    v8s qfB = *(const v8s*)(Qp + (size_t)(n0 + q) * CQKD + 16 + lh * 8);
    attn_ks(K1p, V1p, qfA, qfB, ks, lane, acc, m, lsum);
  }
  mbuf[w][l31] = m;
  sbuf[w][l31] = lsum;
  __syncthreads();
  float mstar = mbuf[qg * 4 + 0][l31];
#pragma unroll
  for (int k = 1; k < 4; ++k) mstar = fmaxf(mstar, mbuf[qg * 4 + k][l31]);
  float L = 0.f;
#pragma unroll
  for (int k = 0; k < 4; ++k) L += sbuf[qg * 4 + k][l31] * exp2_(mbuf[qg * 4 + k][l31] - mstar);
  {
    float sc = exp2_(m - mstar);
#pragma unroll
    for (int s = 0; s < 8; ++s) acc[s] *= sc;
  }
#pragma unroll 1
  for (int r = 1; r < 4; ++r) {
    if (ks == r) {
#pragma unroll
      for (int s = 0; s < 8; ++s)
#pragma unroll
        for (int g = 0; g < 16; ++g)
          cb[qg][s * 32 + (g & 3) + 8 * (g >> 2) + 4 * lh][l31] = acc[s][g];
    }
    __syncthreads();
    if (ks == 0) {
#pragma unroll
      for (int s = 0; s < 8; ++s)
#pragma unroll
        for (int g = 0; g < 16; ++g)
          acc[s][g] += cb[qg][s * 32 + (g & 3) + 8 * (g >> 2) + 4 * lh][l31];
    }
    __syncthreads();
  }
  if (ks == 0) {  // layer-1 epilogue: normalize + gamma + residual -> out1T bf16
    const float rinv = 1.0f / L;
    const float* xb = x + (size_t)b * CDIM * NSEQ + n0 + q;
#pragma unroll
    for (int s = 0; s < 8; ++s) {
#pragma unroll
      for (int j = 0; j < 8; ++j) {
        const int ch = s * 32 + ((2 * j) & 3) + 8 * (j >> 1) + 4 * lh;
        float o0 = g1 * (acc[s][2 * j] * rinv) + xb[(size_t)ch * NSEQ];
        float o1 = g1 * (acc[s][2 * j + 1] * rinv) + xb[(size_t)(ch + 1) * NSEQ];
        *(unsigned*)(&out1T[(size_t)q * 264 + ch]) = pack_bf16(o0, o1);
      }
    }
  }
  __syncthreads();

  // ---- q2 projection (waves 0,1): W2 A-frag 32x32x16 bf16, pre-scaled ----
  if (w < 2) {
    const int qh = w;
    v16f qacc = (v16f)(0.f);
#pragma unroll
    for (int s = 0; s < 16; ++s) {
      v8s af = *(const v8s*)(W2g + (size_t)(s * 64 + lane) * 8);
      v8s bf = *(const v8s*)(out1T + (size_t)(qh * 32 + l31) * 264 + s * 16 + lh * 8);
      qacc = __builtin_amdgcn_mfma_f32_32x32x16_bf16(af, bf, qacc, 0, 0, 0);
    }
#pragma unroll
    for (int rg = 0; rg < 4; ++rg) {
      const int o = 8 * rg + 4 * lh;
      uint2 pk;
      pk.x = pack_bf16(qacc[rg * 4 + 0] + q2b[o + 0] * LOG2E, qacc[rg * 4 + 1] + q2b[o + 1] * LOG2E);
      pk.y = pack_bf16(qacc[rg * 4 + 2] + q2b[o + 2] * LOG2E, qacc[rg * 4 + 3] + q2b[o + 3] * LOG2E);
      *(uint2*)(q2s + (size_t)(qh * 32 + l31) * 32 + o) = pk;
    }
  }
  __syncthreads();

  // ---- layer 2 ----
#pragma unroll
  for (int s = 0; s < 8; ++s) acc[s] = (v16f)(0.f);
  {
    v8s qfA = *(const v8s*)(q2s + (size_t)q * 32 + lh * 8);
    v8s qfB = *(const v8s*)(q2s + (size_t)q * 32 + 16 + lh * 8);
    attn_ks(K2p, V2p, qfA, qfB, ks, lane, acc, m, lsum);
  }
  mbuf[w][l31] = m;
  sbuf[w][l31] = lsum;
  __syncthreads();
  mstar = mbuf[qg * 4 + 0][l31];
#pragma unroll
  for (int k = 1; k < 4; ++k) mstar = fmaxf(mstar, mbuf[qg * 4 + k][l31]);
  L = 0.f;
#pragma unroll
  for (int k = 0; k < 4; ++k) L += sbuf[qg * 4 + k][l31] * exp2_(mbuf[qg * 4 + k][l31] - mstar);
  {
    float sc = exp2_(m - mstar);
#pragma unroll
    for (int s = 0; s < 8; ++s) acc[s] *= sc;
  }
#pragma unroll 1
  for (int r = 1; r < 4; ++r) {
    if (ks == r) {
#pragma unroll
      for (int s = 0; s < 8; ++s)
#pragma unroll
        for (int g = 0; g < 16; ++g)
          cb[qg][s * 32 + (g & 3) + 8 * (g >> 2) + 4 * lh][l31] = acc[s][g];
    }
    __syncthreads();
    if (ks == 0) {
#pragma unroll
      for (int s = 0; s < 8; ++s)
#pragma unroll
        for (int g = 0; g < 16; ++g)
          acc[s][g] += cb[qg][s * 32 + (g & 3) + 8 * (g >> 2) + 4 * lh][l31];
    }
    __syncthreads();
  }
  if (ks == 0) {  // layer-2 epilogue: normalize + gamma + out1 residual -> global
    const float rinv = 1.0f / L;
    float* ob = outp + (size_t)b * CDIM * NSEQ + n0 + q;
#pragma unroll
    for (int s = 0; s < 8; ++s) {
#pragma unroll
      for (int j = 0; j < 8; ++j) {
        const int ch = s * 32 + ((2 * j) & 3) + 8 * (j >> 1) + 4 * lh;
        float r0 = bf2f(out1T[(size_t)q * 264 + ch]);
        float r1 = bf2f(out1T[(size_t)q * 264 + ch + 1]);
        ob[(size_t)ch * NSEQ] = g2 * (acc[s][2 * j] * rinv) + r0;
        ob[(size_t)(ch + 1) * NSEQ] = g2 * (acc[s][2 * j + 1] * rinv) + r1;
      }
    }
  }
}

extern "C" void kernel_launch(void* const* d_in, const int* in_sizes, int n_in,
                              void* d_out, int out_size, void* d_ws, size_t ws_size,
                              hipStream_t stream) {
  const float* x   = (const float*)d_in[0];
  const float* y   = (const float*)d_in[1];
  const float* z   = (const float*)d_in[2];
  const float* q1w = (const float*)d_in[3];
  const float* q1b = (const float*)d_in[4];
  const float* k1w = (const float*)d_in[5];
  const float* k1b = (const float*)d_in[6];
  const float* v1w = (const float*)d_in[7];
  const float* v1b = (const float*)d_in[8];
  const float* g1  = (const float*)d_in[9];
  const float* q2w = (const float*)d_in[10];
  const float* q2b = (const float*)d_in[11];
  const float* k2w = (const float*)d_in[12];
  const float* k2b = (const float*)d_in[13];
  const float* v2w = (const float*)d_in[14];
  const float* v2b = (const float*)d_in[15];
  const float* g2  = (const float*)d_in[16];
  char* ws = (char*)d_ws;
  unsigned short* Wbf = (unsigned short*)(ws);             // 327,680 B
  unsigned short* Q1  = (unsigned short*)(ws + 327680);    // 1 MB
  unsigned short* K1  = (unsigned short*)(ws + 1376256);   // 1 MB
  unsigned short* K2  = (unsigned short*)(ws + 2424832);   // 1 MB
  unsigned char*  V1  = (unsigned char*)(ws + 3473408);    // 4 MB (fp8)
  unsigned char*  V2  = (unsigned char*)(ws + 7667712);    // 4 MB (fp8) -> 11.9 MB total
  float* outp = (float*)d_out;

  convw_kernel<<<dim3(80), 256, 0, stream>>>(q1w, k1w, k2w, q2w, v1w, v2w, Wbf);
  prep_kernel<<<dim3(64, 4, 3), 256, 0, stream>>>(x, y, z, Wbf, q1b, k1b, k2b, v1b,
                                                  v2b, Q1, K1, K2, V1, V2);
  fused_attn_kernel<<<dim3(256), 512, 0, stream>>>(Q1, K1, V1, K2, V2, Wbf + 24576, x,
                                                   q2b, g1, g2, outp);
}

// Round 4
// 230.311 us; speedup vs baseline: 1.0799x; 1.0799x over previous
//
#include <hip/hip_runtime.h>
#include <hip/hip_bf16.h>

#define NSEQ 4096
#define CDIM 256
#define CQKD 32
#define LOG2E 1.4426950408889634f

typedef float v4f __attribute__((ext_vector_type(4)));
typedef float v16f __attribute__((ext_vector_type(16)));
typedef short v8s __attribute__((ext_vector_type(8)));
typedef unsigned long long u64;

__device__ __forceinline__ float exp2_(float x) {
#if __has_builtin(__builtin_amdgcn_exp2f)
  return __builtin_amdgcn_exp2f(x);
#else
  float r;
  __asm__("v_exp_f32 %0, %1" : "=v"(r) : "v"(x));
  return r;
#endif
}

__device__ __forceinline__ unsigned short f2bf(float x) {
  unsigned u = __builtin_bit_cast(unsigned, x);
  unsigned r = (u + 0x7FFFu + ((u >> 16) & 1u)) >> 16;
  return (unsigned short)r;
}
__device__ __forceinline__ float bf2f(unsigned short s) {
  unsigned u = ((unsigned)s) << 16;
  return __builtin_bit_cast(float, u);
}
__device__ __forceinline__ unsigned int pack_bf16(float a, float b) {
#if __has_builtin(__builtin_amdgcn_cvt_pk_bf16_f32)
  typedef __bf16 v2bf __attribute__((ext_vector_type(2)));
  v2bf r = __builtin_amdgcn_cvt_pk_bf16_f32(a, b);
  return __builtin_bit_cast(unsigned int, r);
#else
  return ((unsigned)f2bf(b) << 16) | (unsigned)f2bf(a);
#endif
}

// fp8 e4m3fn (OCP) encode, software fallback
__device__ __forceinline__ unsigned char f2e4m3(float x) {
  unsigned u = __builtin_bit_cast(unsigned, x);
  unsigned s = (u >> 24) & 0x80u;
  unsigned au = u & 0x7fffffffu;
  if (au > 0x43e00000u) return (unsigned char)(s | 0x7eu);  // clamp to 448
  if (au < 0x3c800000u) {                                   // subnormal range (<2^-6)
    float ax = __builtin_bit_cast(float, au);
    int q = (int)(ax * 512.0f + 0.5f);
    if (q > 7) q = 7;
    return (unsigned char)(s | (unsigned)q);
  }
  int e = (int)((au >> 23) & 0xffu) - 127 + 7;
  unsigned m = au & 0x7fffffu;
  unsigned mr = m + 0x7ffffu + ((m >> 20) & 1u);
  if (mr >= 0x800000u) { mr -= 0x800000u; e += 1; if (e >= 16) return (unsigned char)(s | 0x7e); }
  return (unsigned char)(s | ((unsigned)e << 3) | (mr >> 20));
}
__device__ __forceinline__ unsigned int pack4_fp8(float a, float b, float c, float d) {
#if __has_builtin(__builtin_amdgcn_cvt_pk_fp8_f32)
  int v = 0;
  v = __builtin_amdgcn_cvt_pk_fp8_f32(a, b, v, false);
  v = __builtin_amdgcn_cvt_pk_fp8_f32(c, d, v, true);
  return (unsigned int)v;
#else
  return (unsigned)f2e4m3(a) | ((unsigned)f2e4m3(b) << 8) |
         ((unsigned)f2e4m3(c) << 16) | ((unsigned)f2e4m3(d) << 24);
#endif
}

// LDS-only split barrier (orders LDS producer->consumer without draining vmcnt)
__device__ __forceinline__ void barrier_lds() {
  __asm__ __volatile__("s_waitcnt lgkmcnt(0)\n\ts_barrier" ::: "memory");
}

// ---------------- weight convert+frag-pack (bf16) ----------------
__global__ __launch_bounds__(256) void convw_kernel(
    const float* __restrict__ q1w, const float* __restrict__ k1w,
    const float* __restrict__ k2w, const float* __restrict__ q2w,
    const float* __restrict__ v1w, const float* __restrict__ v2w,
    unsigned short* __restrict__ W) {
  const int s = blockIdx.x * 256 + threadIdx.x;  // v8s slot, 20480 total
  const float* src;
  int o, ch0;
  size_t obase;
  float scale = 1.0f;
  if (s < 3072) {
    const int wsel = s >> 10, r = s & 1023;
    src = wsel == 0 ? q1w : (wsel == 1 ? k1w : k2w);
    const int ot = r >> 9, cb = (r >> 6) & 7, lane = r & 63;
    o = ot * 16 + (lane & 15);
    ch0 = cb * 32 + ((lane >> 4) & 3) * 8;
    obase = (size_t)wsel * 8192 + (size_t)r * 8;
  } else if (s < 19456) {
    const int s2 = s - 3072, which = s2 >> 13, r = s2 & 8191;
    src = which == 0 ? v1w : v2w;
    const int ot = r >> 9, cb = (r >> 6) & 7, lane = r & 63;
    o = ot * 16 + (lane & 15);
    ch0 = cb * 32 + ((lane >> 4) & 3) * 8;
    obase = 32768 + (size_t)which * 65536 + (size_t)r * 8;
  } else {
    const int r = s - 19456;
    src = q2w;
    const int lane = r & 63;
    o = lane & 31;
    ch0 = (r >> 6) * 16 + (lane >> 5) * 8;
    obase = 24576 + (size_t)r * 8;
    scale = LOG2E;
  }
#pragma unroll
  for (int j = 0; j < 8; ++j)
    W[obase + j] = f2bf(src[o * CDIM + ch0 + j] * scale);
}

// ---------------- prep: transpose + Q/K/V projections (V emitted fp8) ----------------
__global__ __launch_bounds__(256) void prep_kernel(
    const float* __restrict__ x, const float* __restrict__ y,
    const float* __restrict__ z, const unsigned short* __restrict__ Wbf,
    const float* __restrict__ q1b, const float* __restrict__ k1b,
    const float* __restrict__ k2b, const float* __restrict__ v1b,
    const float* __restrict__ v2b, unsigned short* __restrict__ Q1,
    unsigned short* __restrict__ K1, unsigned short* __restrict__ K2,
    unsigned char* __restrict__ V1, unsigned char* __restrict__ V2) {
  __shared__ unsigned short t[256][72];  // staging [ch][n] bf16; reused as fp8 Vt
  __shared__ unsigned short Kt[64][40];
  const int src = blockIdx.z;
  const float* in = src == 0 ? x : (src == 1 ? y : z);
  const int b = blockIdx.y;
  const int n0 = blockIdx.x * 64;
  const int tid = threadIdx.x, lane = tid & 63, w = tid >> 6;
  const int quad = lane >> 4, r15 = lane & 15, l31 = lane & 31, lh = lane >> 5;
  const float* ip = in + (size_t)(b * CDIM) * NSEQ + n0;
  {
    const int chb = tid >> 4, c4 = (tid & 15) * 4;
#pragma unroll
    for (int p = 0; p < 16; ++p) {
      const int ch = p * 16 + chb;
      float4 v = *(const float4*)(ip + (size_t)ch * NSEQ + c4);
      uint2 pk;
      pk.x = pack_bf16(v.x, v.y);
      pk.y = pack_bf16(v.z, v.w);
      *(uint2*)&t[ch][c4] = pk;
    }
  }
  __syncthreads();
  v8s af[8];
#pragma unroll
  for (int cb = 0; cb < 8; ++cb) {
    union { unsigned short e[8]; v8s v; } u;
#pragma unroll
    for (int j = 0; j < 8; ++j) u.e[j] = t[cb * 32 + quad * 8 + j][w * 16 + r15];
    af[cb] = u.v;
  }
  const int nt = blockIdx.x * 4 + w;
  const unsigned short* Wqk = Wbf + src * 8192;
  v4f a0 = {0.f, 0.f, 0.f, 0.f}, a1 = a0;
#pragma unroll
  for (int cb = 0; cb < 8; ++cb) {
    v8s b0 = *(const v8s*)(Wqk + (size_t)cb * 512 + lane * 8);
    v8s b1 = *(const v8s*)(Wqk + (size_t)(8 + cb) * 512 + lane * 8);
    a0 = __builtin_amdgcn_mfma_f32_16x16x32_bf16(af[cb], b0, a0, 0, 0, 0);
    a1 = __builtin_amdgcn_mfma_f32_16x16x32_bf16(af[cb], b1, a1, 0, 0, 0);
  }
  if (src == 0) {
#pragma unroll
    for (int r = 0; r < 4; ++r) {
      Q1[((size_t)b * NSEQ + nt * 16 + quad * 4 + r) * CQKD + r15] =
          f2bf((a0[r] + q1b[r15]) * LOG2E);
      Q1[((size_t)b * NSEQ + nt * 16 + quad * 4 + r) * CQKD + 16 + r15] =
          f2bf((a1[r] + q1b[16 + r15]) * LOG2E);
    }
    return;
  }
  const float* kbias = src == 1 ? k1b : k2b;
#pragma unroll
  for (int r = 0; r < 4; ++r) {
    Kt[w * 16 + quad * 4 + r][r15] = f2bf(a0[r] + kbias[r15]);
    Kt[w * 16 + quad * 4 + r][16 + r15] = f2bf(a1[r] + kbias[16 + r15]);
  }
  const unsigned short* Wv = Wbf + 32768 + (src - 1) * 65536;
  const float* vbias = src == 1 ? v1b : v2b;
  v4f vacc[16];
#pragma unroll
  for (int ot = 0; ot < 16; ++ot) vacc[ot] = (v4f){0.f, 0.f, 0.f, 0.f};
#pragma unroll
  for (int cb = 0; cb < 8; ++cb) {
    const v8s afc = af[cb];
#pragma unroll
    for (int ot = 0; ot < 16; ++ot) {
      v8s bf = *(const v8s*)(Wv + (size_t)(ot * 8 + cb) * 512 + lane * 8);
      vacc[ot] = __builtin_amdgcn_mfma_f32_16x16x32_bf16(afc, bf, vacc[ot], 0, 0, 0);
    }
  }
  __syncthreads();  // staging reads done -> reuse t as fp8 Vt (rows 72 B)
  unsigned char* Vt8 = (unsigned char*)t;
#pragma unroll
  for (int ot = 0; ot < 16; ++ot) {
    const int ch = ot * 16 + r15;
    const float bv = vbias[ch];
    *(unsigned int*)&Vt8[(size_t)ch * 72 + w * 16 + quad * 4] =
        pack4_fp8(vacc[ot][0] + bv, vacc[ot][1] + bv, vacc[ot][2] + bv, vacc[ot][3] + bv);
  }
  {
    unsigned short* Kout = (src == 1 ? K1 : K2) + (size_t)b * (NSEQ / 16) * 512;
    *(v8s*)(Kout + ((size_t)nt * 64 + lane) * 8) = *(const v8s*)&Kt[w * 16 + r15][quad * 8];
  }
  __syncthreads();  // Vt complete
  unsigned char* Vout = (src == 1 ? V1 : V2) + (size_t)b * (NSEQ / 16) * 8 * 512;
#pragma unroll
  for (int chb = 0; chb < 8; ++chb)
    *(u64*)(Vout + (((size_t)nt * 8 + chb) * 64 + lane) * 8) =
        *(const u64*)&Vt8[(size_t)(chb * 32 + l31) * 72 + w * 16 + lh * 8];
}

// ---------------- fused double attention (fp8 PV), S(t+1) || PV(t) pipeline ----------------
// 512 thr = 8 waves, 64 q/block, grid 256. Wave w: S key-slice kb16=tile*8+w (bf16),
// PV ch-slab chb=w (fp8 32x32x16). Per-q global max from standalone pass keeps
// exp2(s-m) in (0,1] -> e4m3-safe. P fp8 double-buffered in LDS.
// Pipeline: between barriers, S(t+1)->pack->write P[(t+1)&1] runs CONCURRENTLY with
// PV(t) reading P[t&1] — the previously-serial S chain hides under PV's MFMAs.

__device__ __forceinline__ void max_pass(
    const unsigned short* __restrict__ Kp, const v8s qf[4], int w, int lane,
    float (*lbuf)[64], float m[4]) {
  const v4f vzero4 = {0.f, 0.f, 0.f, 0.f};
  const int r15 = lane & 15;
  const unsigned short* Kl = Kp + (size_t)w * 512 + lane * 8;
  v8s kA = *(const v8s*)(Kl);
  v8s kB = *(const v8s*)(Kl + 4096);
#pragma unroll
  for (int qt = 0; qt < 4; ++qt) m[qt] = -3.0e38f;
#pragma unroll 2
  for (int kt = 0; kt < 32; ++kt) {
    v8s kC = *(const v8s*)(Kl + (size_t)((kt + 2) & 31) * 4096);  // depth-2 prefetch
#pragma unroll
    for (int qt = 0; qt < 4; ++qt) {
      v4f st = __builtin_amdgcn_mfma_f32_16x16x32_bf16(kA, qf[qt], vzero4, 0, 0, 0);
      m[qt] = fmaxf(m[qt], fmaxf(fmaxf(st[0], st[1]), fmaxf(st[2], st[3])));
    }
    kA = kB;
    kB = kC;
  }
#pragma unroll
  for (int qt = 0; qt < 4; ++qt) {
    m[qt] = fmaxf(m[qt], __shfl_xor(m[qt], 16));
    m[qt] = fmaxf(m[qt], __shfl_xor(m[qt], 32));
  }
  if (lane < 16) {
#pragma unroll
    for (int qt = 0; qt < 4; ++qt) lbuf[w][qt * 16 + lane] = m[qt];
  }
  __syncthreads();
#pragma unroll
  for (int qt = 0; qt < 4; ++qt) {
    float mm = lbuf[0][qt * 16 + r15];
#pragma unroll
    for (int ww = 1; ww < 8; ++ww) mm = fmaxf(mm, lbuf[ww][qt * 16 + r15]);
    m[qt] = mm;
  }
  __syncthreads();
}

// One pipelined step for tile tt: S(tt+1) with kS -> write P[pbufW]; PV(tt) from
// P[pbufR] with vUse; prefetch K(tt+2)->kOut, V(tt+2)->vUse (after PV reads).
__device__ __forceinline__ void attn_step(
    const unsigned short* __restrict__ Kl, const unsigned char* __restrict__ Vl,
    unsigned char* __restrict__ P, const v8s qf[4], const float m[4], int w, int lane,
    bool doS, int pbufW, int pbufR, int tpre, const v8s kS, v8s& kOut, u64 vUse[8],
    v16f acc[2], float lsum[4]) {
  const v4f vzero4 = {0.f, 0.f, 0.f, 0.f};
  const int quad = (lane >> 4) & 3, r15 = lane & 15;
  const int l31 = lane & 31, lh = lane >> 5;
  // K prefetch (consumed by S two steps ahead)
  kOut = *(const v8s*)(Kl + (size_t)tpre * 4096);
  // S(tt+1) phase (bf16) -> exp2(s - m) -> fp8 P[pbufW]
  if (doS) {
    unsigned char* pw = P + pbufW * 8704 + w * 16 + quad * 4;
#pragma unroll
    for (int qt = 0; qt < 4; ++qt) {
      v4f st = __builtin_amdgcn_mfma_f32_16x16x32_bf16(kS, qf[qt], vzero4, 0, 0, 0);
      float e0 = exp2_(st[0] - m[qt]), e1 = exp2_(st[1] - m[qt]);
      float e2 = exp2_(st[2] - m[qt]), e3 = exp2_(st[3] - m[qt]);
      lsum[qt] += (e0 + e1) + (e2 + e3);
      *(unsigned int*)(pw + (size_t)(qt * 16 + r15) * 136) = pack4_fp8(e0, e1, e2, e3);
    }
  }
  // PV(tt) phase (fp8): 32-ch slab x 128 keys x both 32-q halves
  const unsigned char* pb = P + pbufR * 8704;
#pragma unroll
  for (int s = 0; s < 8; ++s) {
    long pf0 = (long)*(const u64*)(pb + (size_t)l31 * 136 + s * 16 + lh * 8);
    long pf1 = (long)*(const u64*)(pb + (size_t)(32 + l31) * 136 + s * 16 + lh * 8);
    acc[0] = __builtin_amdgcn_mfma_f32_32x32x16_fp8_fp8((long)vUse[s], pf0, acc[0], 0, 0, 0);
    acc[1] = __builtin_amdgcn_mfma_f32_32x32x16_fp8_fp8((long)vUse[s], pf1, acc[1], 0, 0, 0);
  }
  // V prefetch into the slot just consumed (WAR resolved by mfma operand reads)
#pragma unroll
  for (int s = 0; s < 8; ++s)
    vUse[s] = *(const u64*)(Vl + (size_t)tpre * 32768 + s * 4096);
  barrier_lds();
}

__device__ __forceinline__ void attn_loop(
    const unsigned short* __restrict__ Kp, const unsigned char* __restrict__ Vp,
    unsigned char* __restrict__ P, const v8s qf[4], const float m[4], int w, int lane,
    v16f acc[2], float lsum[4]) {
  const v4f vzero4 = {0.f, 0.f, 0.f, 0.f};
  const int quad = lane >> 4, r15 = lane & 15;
  const unsigned short* Kl = Kp + (size_t)w * 512 + lane * 8;
  const unsigned char* Vl = Vp + (size_t)w * 512 + lane * 8;
  v8s kA, kB;
  u64 vA[8], vB[8];
  kA = *(const v8s*)(Kl);  // K(0)
#pragma unroll
  for (int s = 0; s < 8; ++s) vA[s] = *(const u64*)(Vl + (size_t)s * 4096);  // V(0)
  kB = *(const v8s*)(Kl + 4096);  // K(1)
#pragma unroll
  for (int s = 0; s < 8; ++s) vB[s] = *(const u64*)(Vl + 32768 + s * 4096);  // V(1)
  // prologue: S(0) -> P[0]
  {
    unsigned char* pw = P + w * 16 + quad * 4;
#pragma unroll
    for (int qt = 0; qt < 4; ++qt) {
      v4f st = __builtin_amdgcn_mfma_f32_16x16x32_bf16(kA, qf[qt], vzero4, 0, 0, 0);
      float e0 = exp2_(st[0] - m[qt]), e1 = exp2_(st[1] - m[qt]);
      float e2 = exp2_(st[2] - m[qt]), e3 = exp2_(st[3] - m[qt]);
      lsum[qt] += (e0 + e1) + (e2 + e3);
      *(unsigned int*)(pw + (size_t)(qt * 16 + r15) * 136) = pack4_fp8(e0, e1, e2, e3);
    }
  }
  barrier_lds();
  for (int t = 0; t < 32; t += 2) {
    // step tt=t   : S(t+1) w/ kB -> P[1]; PV(t) w/ vA from P[0]; kA<-K(t+2), vA<-V(t+2)
    attn_step(Kl, Vl, P, qf, m, w, lane, true, 1, 0, (t + 2) & 31, kB, kA, vA, acc, lsum);
    // step tt=t+1 : S(t+2) w/ kA -> P[0]; PV(t+1) w/ vB from P[1]; kB<-K(t+3), vB<-V(t+3)
    attn_step(Kl, Vl, P, qf, m, w, lane, t != 30, 0, 1, (t + 3) & 31, kA, kB, vB, acc, lsum);
  }
}

__global__ __launch_bounds__(512, 2) void fused_attn_kernel(
    const unsigned short* __restrict__ Q1g, const unsigned short* __restrict__ K1g,
    const unsigned char* __restrict__ V1g, const unsigned short* __restrict__ K2g,
    const unsigned char* __restrict__ V2g, const unsigned short* __restrict__ W2g,
    const float* __restrict__ x, const float* __restrict__ q2b,
    const float* __restrict__ g1p, const float* __restrict__ g2p,
    float* __restrict__ outp) {
  __shared__ __align__(16) unsigned char P[2 * 8704];        // 17 KB fp8 P
  __shared__ __align__(16) unsigned short out1T[64 * 264];   // 33.8 KB [q][c] bf16
  __shared__ __align__(16) unsigned short q2s[64 * 32];      // 4 KB [q][o]
  __shared__ float lbuf[8][64];

  const int tid = threadIdx.x;
  const int lane = tid & 63;
  const int w = tid >> 6;
  const int quad = lane >> 4;
  const int r15 = lane & 15;
  const int l31 = lane & 31, lh = lane >> 5;
  const int b = blockIdx.x & 3;
  const int n0 = (blockIdx.x >> 2) * 64;

  const float g1 = g1p[0];
  const float g2 = g2p[0];

  const unsigned short* Qp  = Q1g + (size_t)b * NSEQ * CQKD;
  const unsigned short* K1p = K1g + (size_t)b * (NSEQ / 16) * 512;
  const unsigned short* K2p = K2g + (size_t)b * (NSEQ / 16) * 512;
  const unsigned char* V1p  = V1g + (size_t)b * (NSEQ / 16) * 8 * 512;
  const unsigned char* V2p  = V2g + (size_t)b * (NSEQ / 16) * 8 * 512;

  v8s qf[4];
#pragma unroll
  for (int qt = 0; qt < 4; ++qt)
    qf[qt] = *(const v8s*)(Qp + (n0 + qt * 16 + r15) * CQKD + quad * 8);

  v16f acc[2];
  float lsum[4] = {0.f, 0.f, 0.f, 0.f};
  float m[4];
  acc[0] = (v16f)(0.f); acc[1] = (v16f)(0.f);

  // ---- layer 1 ----
  max_pass(K1p, qf, w, lane, lbuf, m);
  attn_loop(K1p, V1p, P, qf, m, w, lane, acc, lsum);
#pragma unroll
  for (int qt = 0; qt < 4; ++qt) {
    lsum[qt] += __shfl_xor(lsum[qt], 16);
    lsum[qt] += __shfl_xor(lsum[qt], 32);
  }
  __syncthreads();
  if (lane < 16) {
#pragma unroll
    for (int qt = 0; qt < 4; ++qt) lbuf[w][qt * 16 + lane] = lsum[qt];
  }
  __syncthreads();
  float rinv[2];
#pragma unroll
  for (int qh = 0; qh < 2; ++qh) {
    const int q = qh * 32 + l31;
    float d = 0.f;
#pragma unroll
    for (int ww = 0; ww < 8; ++ww) d += lbuf[ww][q];
    rinv[qh] = 1.0f / d;
  }
#pragma unroll
  for (int qh = 0; qh < 2; ++qh) {
    const int q = qh * 32 + l31;
#pragma unroll
    for (int rg = 0; rg < 4; ++rg) {
      const int c = w * 32 + 8 * rg + 4 * lh;
      float o0 = g1 * (acc[qh][rg * 4 + 0] * rinv[qh]) + x[((size_t)b * CDIM + c + 0) * NSEQ + n0 + q];
      float o1 = g1 * (acc[qh][rg * 4 + 1] * rinv[qh]) + x[((size_t)b * CDIM + c + 1) * NSEQ + n0 + q];
      float o2 = g1 * (acc[qh][rg * 4 + 2] * rinv[qh]) + x[((size_t)b * CDIM + c + 2) * NSEQ + n0 + q];
      float o3 = g1 * (acc[qh][rg * 4 + 3] * rinv[qh]) + x[((size_t)b * CDIM + c + 3) * NSEQ + n0 + q];
      uint2 pk;
      pk.x = pack_bf16(o0, o1);
      pk.y = pack_bf16(o2, o3);
      *(uint2*)(out1T + (size_t)q * 264 + c) = pk;
    }
  }
  __syncthreads();

  // ---- q2 projection (waves 0,1): W2 A-frag 32x32x16 bf16, pre-scaled ----
  if (w < 2) {
    const int qh = w;
    v16f qacc = (v16f)(0.f);
#pragma unroll
    for (int s = 0; s < 16; ++s) {
      v8s af = *(const v8s*)(W2g + (size_t)(s * 64 + lane) * 8);
      v8s bf = *(const v8s*)(out1T + (size_t)(qh * 32 + l31) * 264 + s * 16 + lh * 8);
      qacc = __builtin_amdgcn_mfma_f32_32x32x16_bf16(af, bf, qacc, 0, 0, 0);
    }
#pragma unroll
    for (int rg = 0; rg < 4; ++rg) {
      const int o = 8 * rg + 4 * lh;
      uint2 pk;
      pk.x = pack_bf16(qacc[rg * 4 + 0] + q2b[o + 0] * LOG2E, qacc[rg * 4 + 1] + q2b[o + 1] * LOG2E);
      pk.y = pack_bf16(qacc[rg * 4 + 2] + q2b[o + 2] * LOG2E, qacc[rg * 4 + 3] + q2b[o + 3] * LOG2E);
      *(uint2*)(q2s + (size_t)(qh * 32 + l31) * 32 + o) = pk;
    }
  }
  __syncthreads();

  // ---- layer 2 ----
#pragma unroll
  for (int qt = 0; qt < 4; ++qt)
    qf[qt] = *(const v8s*)(q2s + (qt * 16 + r15) * 32 + quad * 8);
  acc[0] = (v16f)(0.f); acc[1] = (v16f)(0.f);
#pragma unroll
  for (int qt = 0; qt < 4; ++qt) lsum[qt] = 0.f;
  max_pass(K2p, qf, w, lane, lbuf, m);
  attn_loop(K2p, V2p, P, qf, m, w, lane, acc, lsum);
#pragma unroll
  for (int qt = 0; qt < 4; ++qt) {
    lsum[qt] += __shfl_xor(lsum[qt], 16);
    lsum[qt] += __shfl_xor(lsum[qt], 32);
  }
  __syncthreads();
  if (lane < 16) {
#pragma unroll
    for (int qt = 0; qt < 4; ++qt) lbuf[w][qt * 16 + lane] = lsum[qt];
  }
  __syncthreads();
#pragma unroll
  for (int qh = 0; qh < 2; ++qh) {
    const int q = qh * 32 + l31;
    float d = 0.f;
#pragma unroll
    for (int ww = 0; ww < 8; ++ww) d += lbuf[ww][q];
    rinv[qh] = 1.0f / d;
  }
#pragma unroll
  for (int qh = 0; qh < 2; ++qh) {
    const int q = qh * 32 + l31;
#pragma unroll
    for (int rg = 0; rg < 4; ++rg) {
      const int c = w * 32 + 8 * rg + 4 * lh;
#pragma unroll
      for (int i = 0; i < 4; ++i) {
        float res = bf2f(out1T[(size_t)q * 264 + c + i]);
        outp[((size_t)b * CDIM + c + i) * NSEQ + n0 + q] =
            g2 * (acc[qh][rg * 4 + i] * rinv[qh]) + res;
      }
    }
  }
}

extern "C" void kernel_launch(void* const* d_in, const int* in_sizes, int n_in,
                              void* d_out, int out_size, void* d_ws, size_t ws_size,
                              hipStream_t stream) {
  const float* x   = (const float*)d_in[0];
  const float* y   = (const float*)d_in[1];
  const float* z   = (const float*)d_in[2];
  const float* q1w = (const float*)d_in[3];
  const float* q1b = (const float*)d_in[4];
  const float* k1w = (const float*)d_in[5];
  const float* k1b = (const float*)d_in[6];
  const float* v1w = (const float*)d_in[7];
  const float* v1b = (const float*)d_in[8];
  const float* g1  = (const float*)d_in[9];
  const float* q2w = (const float*)d_in[10];
  const float* q2b = (const float*)d_in[11];
  const float* k2w = (const float*)d_in[12];
  const float* k2b = (const float*)d_in[13];
  const float* v2w = (const float*)d_in[14];
  const float* v2b = (const float*)d_in[15];
  const float* g2  = (const float*)d_in[16];
  char* ws = (char*)d_ws;
  unsigned short* Wbf = (unsigned short*)(ws);             // 327,680 B
  unsigned short* Q1  = (unsigned short*)(ws + 327680);    // 1 MB
  unsigned short* K1  = (unsigned short*)(ws + 1376256);   // 1 MB
  unsigned short* K2  = (unsigned short*)(ws + 2424832);   // 1 MB
  unsigned char*  V1  = (unsigned char*)(ws + 3473408);    // 4 MB (fp8)
  unsigned char*  V2  = (unsigned char*)(ws + 7667712);    // 4 MB (fp8) -> 11.9 MB total
  float* outp = (float*)d_out;

  convw_kernel<<<dim3(80), 256, 0, stream>>>(q1w, k1w, k2w, q2w, v1w, v2w, Wbf);
  prep_kernel<<<dim3(64, 4, 3), 256, 0, stream>>>(x, y, z, Wbf, q1b, k1b, k2b, v1b,
                                                  v2b, Q1, K1, K2, V1, V2);
  fused_attn_kernel<<<dim3(256), 512, 0, stream>>>(Q1, K1, V1, K2, V2, Wbf + 24576, x,
                                                   q2b, g1, g2, outp);
}

// Round 5
// 214.156 us; speedup vs baseline: 1.1614x; 1.0754x over previous
//
#include <hip/hip_runtime.h>
#include <hip/hip_bf16.h>

#define NSEQ 4096
#define CDIM 256
#define CQKD 32
#define LOG2E 1.4426950408889634f

typedef float v4f __attribute__((ext_vector_type(4)));
typedef float v16f __attribute__((ext_vector_type(16)));
typedef short v8s __attribute__((ext_vector_type(8)));
typedef unsigned long long u64;

__device__ __forceinline__ float exp2_(float x) {
#if __has_builtin(__builtin_amdgcn_exp2f)
  return __builtin_amdgcn_exp2f(x);
#else
  float r;
  __asm__("v_exp_f32 %0, %1" : "=v"(r) : "v"(x));
  return r;
#endif
}

__device__ __forceinline__ unsigned short f2bf(float x) {
  unsigned u = __builtin_bit_cast(unsigned, x);
  unsigned r = (u + 0x7FFFu + ((u >> 16) & 1u)) >> 16;
  return (unsigned short)r;
}
__device__ __forceinline__ float bf2f(unsigned short s) {
  unsigned u = ((unsigned)s) << 16;
  return __builtin_bit_cast(float, u);
}
__device__ __forceinline__ unsigned int pack_bf16(float a, float b) {
#if __has_builtin(__builtin_amdgcn_cvt_pk_bf16_f32)
  typedef __bf16 v2bf __attribute__((ext_vector_type(2)));
  v2bf r = __builtin_amdgcn_cvt_pk_bf16_f32(a, b);
  return __builtin_bit_cast(unsigned int, r);
#else
  return ((unsigned)f2bf(b) << 16) | (unsigned)f2bf(a);
#endif
}

// fp8 e4m3fn (OCP) encode, software fallback
__device__ __forceinline__ unsigned char f2e4m3(float x) {
  unsigned u = __builtin_bit_cast(unsigned, x);
  unsigned s = (u >> 24) & 0x80u;
  unsigned au = u & 0x7fffffffu;
  if (au > 0x43e00000u) return (unsigned char)(s | 0x7eu);  // clamp to 448
  if (au < 0x3c800000u) {                                   // subnormal range (<2^-6)
    float ax = __builtin_bit_cast(float, au);
    int q = (int)(ax * 512.0f + 0.5f);
    if (q > 7) q = 7;
    return (unsigned char)(s | (unsigned)q);
  }
  int e = (int)((au >> 23) & 0xffu) - 127 + 7;
  unsigned m = au & 0x7fffffu;
  unsigned mr = m + 0x7ffffu + ((m >> 20) & 1u);
  if (mr >= 0x800000u) { mr -= 0x800000u; e += 1; if (e >= 16) return (unsigned char)(s | 0x7e); }
  return (unsigned char)(s | ((unsigned)e << 3) | (mr >> 20));
}
__device__ __forceinline__ unsigned int pack4_fp8(float a, float b, float c, float d) {
#if __has_builtin(__builtin_amdgcn_cvt_pk_fp8_f32)
  int v = 0;
  v = __builtin_amdgcn_cvt_pk_fp8_f32(a, b, v, false);
  v = __builtin_amdgcn_cvt_pk_fp8_f32(c, d, v, true);
  return (unsigned int)v;
#else
  return (unsigned)f2e4m3(a) | ((unsigned)f2e4m3(b) << 8) |
         ((unsigned)f2e4m3(c) << 16) | ((unsigned)f2e4m3(d) << 24);
#endif
}

// LDS-only split barrier (orders LDS producer->consumer without draining vmcnt)
__device__ __forceinline__ void barrier_lds() {
  __asm__ __volatile__("s_waitcnt lgkmcnt(0)\n\ts_barrier" ::: "memory");
}

// ---------------- weight convert+frag-pack (bf16) ----------------
__global__ __launch_bounds__(256) void convw_kernel(
    const float* __restrict__ q1w, const float* __restrict__ k1w,
    const float* __restrict__ k2w, const float* __restrict__ q2w,
    const float* __restrict__ v1w, const float* __restrict__ v2w,
    unsigned short* __restrict__ W) {
  const int s = blockIdx.x * 256 + threadIdx.x;  // v8s slot, 20480 total
  const float* src;
  int o, ch0;
  size_t obase;
  float scale = 1.0f;
  if (s < 3072) {
    const int wsel = s >> 10, r = s & 1023;
    src = wsel == 0 ? q1w : (wsel == 1 ? k1w : k2w);
    const int ot = r >> 9, cb = (r >> 6) & 7, lane = r & 63;
    o = ot * 16 + (lane & 15);
    ch0 = cb * 32 + ((lane >> 4) & 3) * 8;
    obase = (size_t)wsel * 8192 + (size_t)r * 8;
  } else if (s < 19456) {
    const int s2 = s - 3072, which = s2 >> 13, r = s2 & 8191;
    src = which == 0 ? v1w : v2w;
    const int ot = r >> 9, cb = (r >> 6) & 7, lane = r & 63;
    o = ot * 16 + (lane & 15);
    ch0 = cb * 32 + ((lane >> 4) & 3) * 8;
    obase = 32768 + (size_t)which * 65536 + (size_t)r * 8;
  } else {
    const int r = s - 19456;
    src = q2w;
    const int lane = r & 63;
    o = lane & 31;
    ch0 = (r >> 6) * 16 + (lane >> 5) * 8;
    obase = 24576 + (size_t)r * 8;
    scale = LOG2E;
  }
#pragma unroll
  for (int j = 0; j < 8; ++j)
    W[obase + j] = f2bf(src[o * CDIM + ch0 + j] * scale);
}

// ---------------- prep: transpose + Q/K/V projections (V emitted fp8) ----------------
__global__ __launch_bounds__(256) void prep_kernel(
    const float* __restrict__ x, const float* __restrict__ y,
    const float* __restrict__ z, const unsigned short* __restrict__ Wbf,
    const float* __restrict__ q1b, const float* __restrict__ k1b,
    const float* __restrict__ k2b, const float* __restrict__ v1b,
    const float* __restrict__ v2b, unsigned short* __restrict__ Q1,
    unsigned short* __restrict__ K1, unsigned short* __restrict__ K2,
    unsigned char* __restrict__ V1, unsigned char* __restrict__ V2) {
  __shared__ unsigned short t[256][72];  // staging [ch][n] bf16; reused as fp8 Vt
  __shared__ unsigned short Kt[64][40];
  const int src = blockIdx.z;
  const float* in = src == 0 ? x : (src == 1 ? y : z);
  const int b = blockIdx.y;
  const int n0 = blockIdx.x * 64;
  const int tid = threadIdx.x, lane = tid & 63, w = tid >> 6;
  const int quad = lane >> 4, r15 = lane & 15, l31 = lane & 31, lh = lane >> 5;
  const float* ip = in + (size_t)(b * CDIM) * NSEQ + n0;
  {
    const int chb = tid >> 4, c4 = (tid & 15) * 4;
#pragma unroll
    for (int p = 0; p < 16; ++p) {
      const int ch = p * 16 + chb;
      float4 v = *(const float4*)(ip + (size_t)ch * NSEQ + c4);
      uint2 pk;
      pk.x = pack_bf16(v.x, v.y);
      pk.y = pack_bf16(v.z, v.w);
      *(uint2*)&t[ch][c4] = pk;
    }
  }
  __syncthreads();
  v8s af[8];
#pragma unroll
  for (int cb = 0; cb < 8; ++cb) {
    union { unsigned short e[8]; v8s v; } u;
#pragma unroll
    for (int j = 0; j < 8; ++j) u.e[j] = t[cb * 32 + quad * 8 + j][w * 16 + r15];
    af[cb] = u.v;
  }
  const int nt = blockIdx.x * 4 + w;
  const unsigned short* Wqk = Wbf + src * 8192;
  v4f a0 = {0.f, 0.f, 0.f, 0.f}, a1 = a0;
#pragma unroll
  for (int cb = 0; cb < 8; ++cb) {
    v8s b0 = *(const v8s*)(Wqk + (size_t)cb * 512 + lane * 8);
    v8s b1 = *(const v8s*)(Wqk + (size_t)(8 + cb) * 512 + lane * 8);
    a0 = __builtin_amdgcn_mfma_f32_16x16x32_bf16(af[cb], b0, a0, 0, 0, 0);
    a1 = __builtin_amdgcn_mfma_f32_16x16x32_bf16(af[cb], b1, a1, 0, 0, 0);
  }
  if (src == 0) {
#pragma unroll
    for (int r = 0; r < 4; ++r) {
      Q1[((size_t)b * NSEQ + nt * 16 + quad * 4 + r) * CQKD + r15] =
          f2bf((a0[r] + q1b[r15]) * LOG2E);
      Q1[((size_t)b * NSEQ + nt * 16 + quad * 4 + r) * CQKD + 16 + r15] =
          f2bf((a1[r] + q1b[16 + r15]) * LOG2E);
    }
    return;
  }
  const float* kbias = src == 1 ? k1b : k2b;
#pragma unroll
  for (int r = 0; r < 4; ++r) {
    Kt[w * 16 + quad * 4 + r][r15] = f2bf(a0[r] + kbias[r15]);
    Kt[w * 16 + quad * 4 + r][16 + r15] = f2bf(a1[r] + kbias[16 + r15]);
  }
  const unsigned short* Wv = Wbf + 32768 + (src - 1) * 65536;
  const float* vbias = src == 1 ? v1b : v2b;
  v4f vacc[16];
#pragma unroll
  for (int ot = 0; ot < 16; ++ot) vacc[ot] = (v4f){0.f, 0.f, 0.f, 0.f};
#pragma unroll
  for (int cb = 0; cb < 8; ++cb) {
    const v8s afc = af[cb];
#pragma unroll
    for (int ot = 0; ot < 16; ++ot) {
      v8s bf = *(const v8s*)(Wv + (size_t)(ot * 8 + cb) * 512 + lane * 8);
      vacc[ot] = __builtin_amdgcn_mfma_f32_16x16x32_bf16(afc, bf, vacc[ot], 0, 0, 0);
    }
  }
  __syncthreads();  // staging reads done -> reuse t as fp8 Vt (rows 72 B)
  unsigned char* Vt8 = (unsigned char*)t;
#pragma unroll
  for (int ot = 0; ot < 16; ++ot) {
    const int ch = ot * 16 + r15;
    const float bv = vbias[ch];
    *(unsigned int*)&Vt8[(size_t)ch * 72 + w * 16 + quad * 4] =
        pack4_fp8(vacc[ot][0] + bv, vacc[ot][1] + bv, vacc[ot][2] + bv, vacc[ot][3] + bv);
  }
  {
    unsigned short* Kout = (src == 1 ? K1 : K2) + (size_t)b * (NSEQ / 16) * 512;
    *(v8s*)(Kout + ((size_t)nt * 64 + lane) * 8) = *(const v8s*)&Kt[w * 16 + r15][quad * 8];
  }
  __syncthreads();  // Vt complete
  unsigned char* Vout = (src == 1 ? V1 : V2) + (size_t)b * (NSEQ / 16) * 8 * 512;
#pragma unroll
  for (int chb = 0; chb < 8; ++chb)
    *(u64*)(Vout + (((size_t)nt * 8 + chb) * 64 + lane) * 8) =
        *(const u64*)&Vt8[(size_t)(chb * 32 + l31) * 72 + w * 16 + lh * 8];
}

// ---------------- fused double attention: producer/consumer wave split ----------------
// 1024 thr = 16 waves, 64 q/block, grid 256 (1 block/CU, 4 waves/SIMD).
// Waves 0-7: S-PRODUCERS — per tile: 1 K load, 4x mfma16x16x32 bf16 (16-key slice),
//   exp2(s-m), fp8 pack, write P slice. Waves 8-15: PV-CONSUMERS — per tile:
//   16 V loads, 16 P LDS reads, 16x mfma32x32x16 fp8 into the 32-ch slab acc.
// Each SIMD holds 2 S + 2 PV waves -> anti-correlated phases hide each other's
// latency. One lgkmcnt-only barrier per tile (vmcnt stays in flight). P double-
// buffered: S writes buf (t+1)&1 while PV reads buf t&1. Per-q global max from
// 16-wave max_pass keeps exp2(s-m) in (0,1] -> e4m3-safe.

__device__ __forceinline__ void max_pass16(
    const unsigned short* __restrict__ Kp, const v8s qf[4], int w, int lane,
    float (*lbuf)[64], float m[4]) {
  const v4f vzero4 = {0.f, 0.f, 0.f, 0.f};
  const int r15 = lane & 15;
  const unsigned short* Kl = Kp + (size_t)w * 512 + lane * 8;
  v8s kA = *(const v8s*)(Kl);
  v8s kB = *(const v8s*)(Kl + 8192);
#pragma unroll
  for (int qt = 0; qt < 4; ++qt) m[qt] = -3.0e38f;
#pragma unroll 2
  for (int kt = 0; kt < 16; ++kt) {
    v8s kC = *(const v8s*)(Kl + (size_t)((kt + 2) & 15) * 8192);  // depth-2 prefetch
#pragma unroll
    for (int qt = 0; qt < 4; ++qt) {
      v4f st = __builtin_amdgcn_mfma_f32_16x16x32_bf16(kA, qf[qt], vzero4, 0, 0, 0);
      m[qt] = fmaxf(m[qt], fmaxf(fmaxf(st[0], st[1]), fmaxf(st[2], st[3])));
    }
    kA = kB;
    kB = kC;
  }
#pragma unroll
  for (int qt = 0; qt < 4; ++qt) {
    m[qt] = fmaxf(m[qt], __shfl_xor(m[qt], 16));
    m[qt] = fmaxf(m[qt], __shfl_xor(m[qt], 32));
  }
  if (lane < 16) {
#pragma unroll
    for (int qt = 0; qt < 4; ++qt) lbuf[w][qt * 16 + lane] = m[qt];
  }
  __syncthreads();
#pragma unroll
  for (int qt = 0; qt < 4; ++qt) {
    float mm = lbuf[0][qt * 16 + r15];
#pragma unroll
    for (int ww = 1; ww < 16; ++ww) mm = fmaxf(mm, lbuf[ww][qt * 16 + r15]);
    m[qt] = mm;
  }
  __syncthreads();
}

__device__ __forceinline__ void s_phase(
    unsigned char* __restrict__ P, int pbuf, const v8s kf, const v8s qf[4],
    const float m[4], int w, int lane, float lsum[4]) {
  const v4f vzero4 = {0.f, 0.f, 0.f, 0.f};
  const int quad = lane >> 4, r15 = lane & 15;
  unsigned char* pw = P + pbuf * 8704 + w * 16 + quad * 4;
#pragma unroll
  for (int qt = 0; qt < 4; ++qt) {
    v4f st = __builtin_amdgcn_mfma_f32_16x16x32_bf16(kf, qf[qt], vzero4, 0, 0, 0);
    float e0 = exp2_(st[0] - m[qt]), e1 = exp2_(st[1] - m[qt]);
    float e2 = exp2_(st[2] - m[qt]), e3 = exp2_(st[3] - m[qt]);
    lsum[qt] += (e0 + e1) + (e2 + e3);
    *(unsigned int*)(pw + (size_t)(qt * 16 + r15) * 136) = pack4_fp8(e0, e1, e2, e3);
  }
}

__device__ __forceinline__ void attn_loop(
    const unsigned short* __restrict__ Kp, const unsigned char* __restrict__ Vp,
    unsigned char* __restrict__ P, const v8s qf[4], const float m[4], int w, int lane,
    v16f acc[2], float lsum[4]) {
  if (w < 8) {
    // ---- S producer ----
    const unsigned short* Kl = Kp + (size_t)w * 512 + lane * 8;
    v8s kA = *(const v8s*)(Kl);
    v8s kB = *(const v8s*)(Kl + 4096);
    s_phase(P, 0, kA, qf, m, w, lane, lsum);
    barrier_lds();
#pragma unroll 2
    for (int t = 0; t < 32; ++t) {
      v8s kC = *(const v8s*)(Kl + (size_t)((t + 2) & 31) * 4096);
      if (t < 31) s_phase(P, (t + 1) & 1, kB, qf, m, w, lane, lsum);
      kA = kB;
      kB = kC;
      barrier_lds();
    }
  } else {
    // ---- PV consumer ----
    const int l31 = lane & 31, lh = lane >> 5;
    const unsigned char* Vl = Vp + (size_t)(w - 8) * 512 + lane * 8;
    u64 vA[8], vB[8];
#pragma unroll
    for (int s = 0; s < 8; ++s) vA[s] = *(const u64*)(Vl + (size_t)s * 4096);
    barrier_lds();
#pragma unroll 2
    for (int t = 0; t < 32; ++t) {
      // prefetch next tile's V (in flight across the barrier)
#pragma unroll
      for (int s = 0; s < 8; ++s)
        vB[s] = *(const u64*)(Vl + (size_t)((t + 1) & 31) * 32768 + s * 4096);
      const unsigned char* pb = P + (t & 1) * 8704;
#pragma unroll
      for (int s = 0; s < 8; ++s) {
        long pf0 = (long)*(const u64*)(pb + (size_t)l31 * 136 + s * 16 + lh * 8);
        long pf1 = (long)*(const u64*)(pb + (size_t)(32 + l31) * 136 + s * 16 + lh * 8);
        acc[0] = __builtin_amdgcn_mfma_f32_32x32x16_fp8_fp8((long)vA[s], pf0, acc[0], 0, 0, 0);
        acc[1] = __builtin_amdgcn_mfma_f32_32x32x16_fp8_fp8((long)vA[s], pf1, acc[1], 0, 0, 0);
      }
#pragma unroll
      for (int s = 0; s < 8; ++s) vA[s] = vB[s];
      barrier_lds();
    }
  }
}

__global__ __launch_bounds__(1024, 4) void fused_attn_kernel(
    const unsigned short* __restrict__ Q1g, const unsigned short* __restrict__ K1g,
    const unsigned char* __restrict__ V1g, const unsigned short* __restrict__ K2g,
    const unsigned char* __restrict__ V2g, const unsigned short* __restrict__ W2g,
    const float* __restrict__ x, const float* __restrict__ q2b,
    const float* __restrict__ g1p, const float* __restrict__ g2p,
    float* __restrict__ outp) {
  __shared__ __align__(16) unsigned char P[2 * 8704];        // 17 KB fp8 P
  __shared__ __align__(16) unsigned short out1T[64 * 264];   // 33.8 KB [q][c] bf16
  __shared__ __align__(16) unsigned short q2s[64 * 32];      // 4 KB [q][o]
  __shared__ float lbuf[16][64];                             // 4 KB

  const int tid = threadIdx.x;
  const int lane = tid & 63;
  const int w = tid >> 6;        // 0..15; 0-7 = S producers, 8-15 = PV consumers
  const int quad = lane >> 4;
  const int r15 = lane & 15;
  const int l31 = lane & 31, lh = lane >> 5;
  const int b = blockIdx.x & 3;
  const int n0 = (blockIdx.x >> 2) * 64;

  const float g1 = g1p[0];
  const float g2 = g2p[0];

  const unsigned short* Qp  = Q1g + (size_t)b * NSEQ * CQKD;
  const unsigned short* K1p = K1g + (size_t)b * (NSEQ / 16) * 512;
  const unsigned short* K2p = K2g + (size_t)b * (NSEQ / 16) * 512;
  const unsigned char* V1p  = V1g + (size_t)b * (NSEQ / 16) * 8 * 512;
  const unsigned char* V2p  = V2g + (size_t)b * (NSEQ / 16) * 8 * 512;

  v8s qf[4];
#pragma unroll
  for (int qt = 0; qt < 4; ++qt)
    qf[qt] = *(const v8s*)(Qp + (n0 + qt * 16 + r15) * CQKD + quad * 8);

  v16f acc[2];
  float lsum[4] = {0.f, 0.f, 0.f, 0.f};
  float m[4];
  acc[0] = (v16f)(0.f); acc[1] = (v16f)(0.f);

  // ---- layer 1 ----
  max_pass16(K1p, qf, w, lane, lbuf, m);
  attn_loop(K1p, V1p, P, qf, m, w, lane, acc, lsum);
  // lsum reduce: S-waves only hold it
  if (w < 8) {
#pragma unroll
    for (int qt = 0; qt < 4; ++qt) {
      lsum[qt] += __shfl_xor(lsum[qt], 16);
      lsum[qt] += __shfl_xor(lsum[qt], 32);
    }
    if (lane < 16) {
#pragma unroll
      for (int qt = 0; qt < 4; ++qt) lbuf[w][qt * 16 + lane] = lsum[qt];
    }
  }
  __syncthreads();
  float rinv[2];
#pragma unroll
  for (int qh = 0; qh < 2; ++qh) {
    const int q = qh * 32 + l31;
    float d = 0.f;
#pragma unroll
    for (int ww = 0; ww < 8; ++ww) d += lbuf[ww][q];
    rinv[qh] = 1.0f / d;
  }
  if (w >= 8) {  // layer-1 epilogue by PV waves (they hold acc)
    const int cw = (w - 8) * 32;
#pragma unroll
    for (int qh = 0; qh < 2; ++qh) {
      const int q = qh * 32 + l31;
#pragma unroll
      for (int rg = 0; rg < 4; ++rg) {
        const int c = cw + 8 * rg + 4 * lh;
        float o0 = g1 * (acc[qh][rg * 4 + 0] * rinv[qh]) + x[((size_t)b * CDIM + c + 0) * NSEQ + n0 + q];
        float o1 = g1 * (acc[qh][rg * 4 + 1] * rinv[qh]) + x[((size_t)b * CDIM + c + 1) * NSEQ + n0 + q];
        float o2 = g1 * (acc[qh][rg * 4 + 2] * rinv[qh]) + x[((size_t)b * CDIM + c + 2) * NSEQ + n0 + q];
        float o3 = g1 * (acc[qh][rg * 4 + 3] * rinv[qh]) + x[((size_t)b * CDIM + c + 3) * NSEQ + n0 + q];
        uint2 pk;
        pk.x = pack_bf16(o0, o1);
        pk.y = pack_bf16(o2, o3);
        *(uint2*)(out1T + (size_t)q * 264 + c) = pk;
      }
    }
  }
  __syncthreads();

  // ---- q2 projection (waves 0,1): W2 A-frag 32x32x16 bf16, pre-scaled ----
  if (w < 2) {
    const int qh = w;
    v16f qacc = (v16f)(0.f);
#pragma unroll
    for (int s = 0; s < 16; ++s) {
      v8s af = *(const v8s*)(W2g + (size_t)(s * 64 + lane) * 8);
      v8s bf = *(const v8s*)(out1T + (size_t)(qh * 32 + l31) * 264 + s * 16 + lh * 8);
      qacc = __builtin_amdgcn_mfma_f32_32x32x16_bf16(af, bf, qacc, 0, 0, 0);
    }
#pragma unroll
    for (int rg = 0; rg < 4; ++rg) {
      const int o = 8 * rg + 4 * lh;
      uint2 pk;
      pk.x = pack_bf16(qacc[rg * 4 + 0] + q2b[o + 0] * LOG2E, qacc[rg * 4 + 1] + q2b[o + 1] * LOG2E);
      pk.y = pack_bf16(qacc[rg * 4 + 2] + q2b[o + 2] * LOG2E, qacc[rg * 4 + 3] + q2b[o + 3] * LOG2E);
      *(uint2*)(q2s + (size_t)(qh * 32 + l31) * 32 + o) = pk;
    }
  }
  __syncthreads();

  // ---- layer 2 ----
#pragma unroll
  for (int qt = 0; qt < 4; ++qt)
    qf[qt] = *(const v8s*)(q2s + (qt * 16 + r15) * 32 + quad * 8);
  acc[0] = (v16f)(0.f); acc[1] = (v16f)(0.f);
#pragma unroll
  for (int qt = 0; qt < 4; ++qt) lsum[qt] = 0.f;
  max_pass16(K2p, qf, w, lane, lbuf, m);
  attn_loop(K2p, V2p, P, qf, m, w, lane, acc, lsum);
  if (w < 8) {
#pragma unroll
    for (int qt = 0; qt < 4; ++qt) {
      lsum[qt] += __shfl_xor(lsum[qt], 16);
      lsum[qt] += __shfl_xor(lsum[qt], 32);
    }
    if (lane < 16) {
#pragma unroll
      for (int qt = 0; qt < 4; ++qt) lbuf[w][qt * 16 + lane] = lsum[qt];
    }
  }
  __syncthreads();
#pragma unroll
  for (int qh = 0; qh < 2; ++qh) {
    const int q = qh * 32 + l31;
    float d = 0.f;
#pragma unroll
    for (int ww = 0; ww < 8; ++ww) d += lbuf[ww][q];
    rinv[qh] = 1.0f / d;
  }
  if (w >= 8) {  // layer-2 epilogue by PV waves
    const int cw = (w - 8) * 32;
#pragma unroll
    for (int qh = 0; qh < 2; ++qh) {
      const int q = qh * 32 + l31;
#pragma unroll
      for (int rg = 0; rg < 4; ++rg) {
        const int c = cw + 8 * rg + 4 * lh;
#pragma unroll
        for (int i = 0; i < 4; ++i) {
          float res = bf2f(out1T[(size_t)q * 264 + c + i]);
          outp[((size_t)b * CDIM + c + i) * NSEQ + n0 + q] =
              g2 * (acc[qh][rg * 4 + i] * rinv[qh]) + res;
        }
      }
    }
  }
}

extern "C" void kernel_launch(void* const* d_in, const int* in_sizes, int n_in,
                              void* d_out, int out_size, void* d_ws, size_t ws_size,
                              hipStream_t stream) {
  const float* x   = (const float*)d_in[0];
  const float* y   = (const float*)d_in[1];
  const float* z   = (const float*)d_in[2];
  const float* q1w = (const float*)d_in[3];
  const float* q1b = (const float*)d_in[4];
  const float* k1w = (const float*)d_in[5];
  const float* k1b = (const float*)d_in[6];
  const float* v1w = (const float*)d_in[7];
  const float* v1b = (const float*)d_in[8];
  const float* g1  = (const float*)d_in[9];
  const float* q2w = (const float*)d_in[10];
  const float* q2b = (const float*)d_in[11];
  const float* k2w = (const float*)d_in[12];
  const float* k2b = (const float*)d_in[13];
  const float* v2w = (const float*)d_in[14];
  const float* v2b = (const float*)d_in[15];
  const float* g2  = (const float*)d_in[16];
  char* ws = (char*)d_ws;
  unsigned short* Wbf = (unsigned short*)(ws);             // 327,680 B
  unsigned short* Q1  = (unsigned short*)(ws + 327680);    // 1 MB
  unsigned short* K1  = (unsigned short*)(ws + 1376256);   // 1 MB
  unsigned short* K2  = (unsigned short*)(ws + 2424832);   // 1 MB
  unsigned char*  V1  = (unsigned char*)(ws + 3473408);    // 4 MB (fp8)
  unsigned char*  V2  = (unsigned char*)(ws + 7667712);    // 4 MB (fp8) -> 11.9 MB total
  float* outp = (float*)d_out;

  convw_kernel<<<dim3(80), 256, 0, stream>>>(q1w, k1w, k2w, q2w, v1w, v2w, Wbf);
  prep_kernel<<<dim3(64, 4, 3), 256, 0, stream>>>(x, y, z, Wbf, q1b, k1b, k2b, v1b,
                                                  v2b, Q1, K1, K2, V1, V2);
  fused_attn_kernel<<<dim3(256), 1024, 0, stream>>>(Q1, K1, V1, K2, V2, Wbf + 24576, x,
                                                    q2b, g1, g2, outp);
}